// Round 19
// baseline (138.905 us; speedup 1.0000x reference)
//
#include <hip/hip_runtime.h>
#include <stdint.h>

typedef unsigned long long ull;
typedef unsigned int u32;
typedef unsigned short u16;
typedef _Float16 f16x8 __attribute__((ext_vector_type(8)));
typedef float f32x4 __attribute__((ext_vector_type(4)));

#define NPGC 512
#define EPGC 4096
#define NTHREADS 512
#define ETOT 4194304
#define ADJCAP 4608           // 4096 edges + <=1 pad per row (pair-padded)
#define CGCAP 416             // ceil(410/16)*16 fp16x8 gate rows
#define SENT 512              // sentinel slot (zero features)

__global__ __launch_bounds__(NTHREADS, 6)
void gce_kernel(const float* __restrict__ x,
                const float* __restrict__ Wc,
                const float* __restrict__ bc,
                const float* __restrict__ pvec,
                const float* __restrict__ Wg,
                const float* __restrict__ bg,
                const int* __restrict__ ei,
                float* __restrict__ out)
{
    __shared__ float4 Clo[NPGC + 1];             //  8208 B features ch0-3 (by slot); 512 = zeros
    __shared__ float4 Chi[NPGC + 1];             //  8208 B features ch4-7; [448..512) = r1/r2 in P7
    __shared__ __align__(4) u16 adjl[ADJCAP];    //  9216 B CSR, pair-padded, slot-rewritten/layer
    __shared__ u16    indptr[NPGC + 1];          //  1026 B row offsets (by original id)
    __shared__ u16    remap[NPGC + 1];           //  1026 B prev slot -> new slot (SENT = dropped)
    __shared__ u16    orig16[NPGC];              //  1024 B slot -> original id
    __shared__ __align__(16) uint4 pool[CGCAP];  //  6656 B: keyv u64[512] | Cg fp16x8[416]
    __shared__ u32    hist[NPGC];                //  2048 B histogram/cum
    __shared__ u32    hoff[NPGC];                //  2048 B placement offsets
    __shared__ u32    wsum8[8];                  //    32 B cross-wave prefix
    // total ~39.5 KB -> 4 blocks/CU

    const int tid  = threadIdx.x;
    const int lane = tid & 63;
    const int grp  = tid >> 6;      // wave id (0..7)
    const int g    = blockIdx.x;

    ull* keyv = reinterpret_cast<ull*>(pool);
    // r1/r2 in dead feature slots: ranks >= 410 never written/read after layer-0 compaction
    float* r1 = reinterpret_cast<float*>(&Clo[448]);
    float* r2 = reinterpret_cast<float*>(&Chi[448]);

    // ---- MFMA gate operands: wave's channel tile ct = grp&3, node-tile start ntb
    const int ct  = grp & 3;
    const int ntb = grp >> 2;
    f16x8 wgf;                       // B-frag: lanes 0-15 = Wg[0..7][ct*16+lane]; rest 0 (k>=8 dead)
    if (lane < 16) {
#pragma unroll
        for (int j = 0; j < 8; ++j) wgf[j] = (_Float16)Wg[j * 64 + ct * 16 + lane];
    } else {
#pragma unroll
        for (int j = 0; j < 8; ++j) wgf[j] = (_Float16)0.f;
    }
    const float bgc = bg[ct * 16 + (lane & 15)];

    // ---- preload this thread's 8 edges, packed (src | dst<<16), local ids
    uint32_t er[8];
    {
        const int* rowp = ei;
        const int* colp = ei + ETOT;
        const size_t eb = (size_t)g * EPGC + (size_t)tid * 8;
#pragma unroll
        for (int i = 0; i < 2; ++i) {
            int4 r4 = *reinterpret_cast<const int4*>(rowp + eb + i * 4);
            int4 c4 = *reinterpret_cast<const int4*>(colp + eb + i * 4);
            er[i * 4 + 0] = (uint32_t)(r4.x & 511) | ((uint32_t)(c4.x & 511) << 16);
            er[i * 4 + 1] = (uint32_t)(r4.y & 511) | ((uint32_t)(c4.y & 511) << 16);
            er[i * 4 + 2] = (uint32_t)(r4.z & 511) | ((uint32_t)(c4.z & 511) << 16);
            er[i * 4 + 3] = (uint32_t)(r4.w & 511) | ((uint32_t)(c4.w & 511) << 16);
        }
    }

    // ---- init: features (slot = original id at layer 0), maps, zero slot
    {
        const float* xr = x + ((size_t)g * NPGC + tid) * 8;
        Clo[tid] = *reinterpret_cast<const float4*>(xr);
        Chi[tid] = *reinterpret_cast<const float4*>(xr + 4);
        orig16[tid] = (u16)tid;
        hist[tid] = 0u;
        if (tid == 0) {
            remap[SENT] = (u16)SENT;
            Clo[SENT] = make_float4(0.f, 0.f, 0.f, 0.f);
            Chi[SENT] = make_float4(0.f, 0.f, 0.f, 0.f);
        }
    }
    __syncthreads();

    // ---- build pair-padded in-edge CSR once (pad entry = SENT)
#pragma unroll
    for (int i = 0; i < 8; ++i) atomicAdd(&hist[er[i] >> 16], 1u);
    __syncthreads();
    {
        const u32 hv  = hist[tid];
        const u32 hvp = (hv + 1u) & ~1u;        // pair-padded row length
        u32 sc = hvp;
#pragma unroll
        for (int d = 1; d < 64; d <<= 1) {
            const u32 t = __shfl_up(sc, (unsigned)d, 64);
            if (lane >= d) sc += t;
        }
        if (lane == 63) wsum8[grp] = sc;
        __syncthreads();
        u32 woff = 0;
#pragma unroll
        for (int w = 0; w < 7; ++w) woff += (w < grp) ? wsum8[w] : 0u;
        const u32 excl = sc + woff - hvp;
        indptr[tid] = (u16)excl;
        hoff[tid]   = excl;
        if (tid == NPGC - 1) indptr[NPGC] = (u16)(excl + hvp);
    }
    __syncthreads();
#pragma unroll
    for (int i = 0; i < 8; ++i) {
        const u32 d = er[i] >> 16, s = er[i] & 0xffffu;
        const u32 pos = atomicAdd(&hoff[d], 1u);
        adjl[pos] = (u16)s;                     // original id = layer-0 slot
    }
    __syncthreads();
    for (u32 j = hoff[tid]; j < (u32)indptr[tid + 1]; ++j) adjl[j] = (u16)SENT;
    // (no barrier needed: pads are in this thread's own row; B2 covers cross-thread reads)

    int   kkprev  = NPGC;
    float out_acc = 0.f;

#pragma unroll 1
    for (int layer = 0; layer < 4; ++layer) {
        const float* Wl = Wc + layer * 64;
        const float* bl = bc + layer * 8;
        const float* pl = pvec + layer * 8;
        const int kk = (layer == 0) ? 410 : (layer == 1) ? 328 : (layer == 2) ? 263 : 211;
        const bool valid = tid < kkprev;
        int me = 0, ib = 0, ie = 0;
        float dinv = 0.f;
        float4 slo = make_float4(0.f, 0.f, 0.f, 0.f), shi = slo;

        // ---- Phase A: (layers>0) rewrite row to new slot space + deg; scale own h
        if (valid) {
            me = orig16[tid];
            ib = indptr[me];
            ie = indptr[me + 1];
            int dg = 1;                          // self-loop
            if (layer == 0) {
                dg += (ie - ib) - ((ie > ib && adjl[ie - 1] == (u16)SENT) ? 1 : 0);
            } else {
                int j = ib;
                for (; j + 4 <= ie; j += 4) {    // 2 pairs per iter (independent chains)
                    const u32 prA = *reinterpret_cast<const u32*>(&adjl[j]);
                    const u32 prB = *reinterpret_cast<const u32*>(&adjl[j + 2]);
                    const u32 a0 = remap[prA & 0xffffu];
                    const u32 a1 = remap[prA >> 16];
                    const u32 b0 = remap[prB & 0xffffu];
                    const u32 b1 = remap[prB >> 16];
                    dg += (a0 != SENT) + (a1 != SENT) + (b0 != SENT) + (b1 != SENT);
                    *reinterpret_cast<u32*>(&adjl[j])     = a0 | (a1 << 16);
                    *reinterpret_cast<u32*>(&adjl[j + 2]) = b0 | (b1 << 16);
                }
                if (j < ie) {
                    const u32 pr = *reinterpret_cast<const u32*>(&adjl[j]);
                    const u32 t0 = remap[pr & 0xffffu];
                    const u32 t1 = remap[pr >> 16];
                    dg += (t0 != SENT) + (t1 != SENT);
                    *reinterpret_cast<u32*>(&adjl[j]) = t0 | (t1 << 16);
                }
            }
            dinv = rsqrtf((float)dg);
            slo = Clo[tid]; shi = Chi[tid];
            slo.x *= dinv; slo.y *= dinv; slo.z *= dinv; slo.w *= dinv;
            shi.x *= dinv; shi.y *= dinv; shi.z *= dinv; shi.w *= dinv;
            Clo[tid] = slo; Chi[tid] = shi;      // h' = h * dinv
        }
        hist[tid] = 0u;
        hoff[tid] = 0u;
        __syncthreads();                        // B2: h' + rewritten rows + clears visible

        // ---- Phase B: direct-slot gather (2-pair unrolled); @W; bias/relu/score/key
        float v0 = 0.f, v1 = 0.f, v2 = 0.f, v3 = 0.f,
              v4 = 0.f, v5 = 0.f, v6 = 0.f, v7 = 0.f;
        float s0 = 0.f;
        int bin0 = 0;
        ull rec0 = 0;
        if (valid) {
            float a0 = slo.x, a1 = slo.y, a2 = slo.z, a3 = slo.w;
            float a4 = shi.x, a5 = shi.y, a6 = shi.z, a7 = shi.w;
            int j = ib;
            for (; j + 4 <= ie; j += 4) {
                const u32 prA = *reinterpret_cast<const u32*>(&adjl[j]);
                const u32 prB = *reinterpret_cast<const u32*>(&adjl[j + 2]);
                const int tA0 = prA & 0xffffu, tA1 = prA >> 16;
                const int tB0 = prB & 0xffffu, tB1 = prB >> 16;
                const float4 lA0 = Clo[tA0], hA0 = Chi[tA0];
                const float4 lA1 = Clo[tA1], hA1 = Chi[tA1];
                a0 += lA0.x + lA1.x; a1 += lA0.y + lA1.y;
                a2 += lA0.z + lA1.z; a3 += lA0.w + lA1.w;
                a4 += hA0.x + hA1.x; a5 += hA0.y + hA1.y;
                a6 += hA0.z + hA1.z; a7 += hA0.w + hA1.w;
                const float4 lB0 = Clo[tB0], hB0 = Chi[tB0];
                const float4 lB1 = Clo[tB1], hB1 = Chi[tB1];
                a0 += lB0.x + lB1.x; a1 += lB0.y + lB1.y;
                a2 += lB0.z + lB1.z; a3 += lB0.w + lB1.w;
                a4 += hB0.x + hB1.x; a5 += hB0.y + hB1.y;
                a6 += hB0.z + hB1.z; a7 += hB0.w + hB1.w;
            }
            if (j < ie) {
                const u32 pr = *reinterpret_cast<const u32*>(&adjl[j]);
                const int t0 = pr & 0xffffu, t1 = pr >> 16;
                const float4 l0 = Clo[t0], h0 = Chi[t0];
                const float4 l1 = Clo[t1], h1 = Chi[t1];
                a0 += l0.x + l1.x; a1 += l0.y + l1.y;
                a2 += l0.z + l1.z; a3 += l0.w + l1.w;
                a4 += h0.x + h1.x; a5 += h0.y + h1.y;
                a6 += h0.z + h1.z; a7 += h0.w + h1.w;
            }
            a0 *= dinv; a1 *= dinv; a2 *= dinv; a3 *= dinv;
            a4 *= dinv; a5 *= dinv; a6 *= dinv; a7 *= dinv;
            const float av[8] = {a0, a1, a2, a3, a4, a5, a6, a7};
            float yv[8];
#pragma unroll
            for (int k = 0; k < 8; ++k) {
                float acc = 0.f;
#pragma unroll
                for (int j2 = 0; j2 < 8; ++j2) acc += av[j2] * Wl[j2 * 8 + k];
                yv[k] = acc;
            }
            float pv[8], ss = 0.f;
#pragma unroll
            for (int k = 0; k < 8; ++k) { pv[k] = pl[k]; ss += pv[k] * pv[k]; }
            float dot = 0.f;
            v0 = fmaxf(yv[0] + bl[0], 0.f); dot += v0 * pv[0];
            v1 = fmaxf(yv[1] + bl[1], 0.f); dot += v1 * pv[1];
            v2 = fmaxf(yv[2] + bl[2], 0.f); dot += v2 * pv[2];
            v3 = fmaxf(yv[3] + bl[3], 0.f); dot += v3 * pv[3];
            v4 = fmaxf(yv[4] + bl[4], 0.f); dot += v4 * pv[4];
            v5 = fmaxf(yv[5] + bl[5], 0.f); dot += v5 * pv[5];
            v6 = fmaxf(yv[6] + bl[6], 0.f); dot += v6 * pv[6];
            v7 = fmaxf(yv[7] + bl[7], 0.f); dot += v7 * pv[7];
            // fast tanh: monotone, NaN-free (e2=inf -> 1, e2=0 -> -1)
            const float xx = dot * rsqrtf(ss);
            const float e2 = __expf(2.0f * xx);
            s0 = 1.0f - 2.0f * __builtin_amdgcn_rcpf(e2 + 1.0f);
            const unsigned ub  = __float_as_uint(s0);
            const unsigned asc = (ub & 0x80000000u) ? ~ub : (ub | 0x80000000u);
            rec0 = ((ull)(~asc) << 32) | (u32)me;    // desc score; ties by original id asc
            int b = (int)((1.0f - s0) * 256.0f);     // monotone with key
            bin0 = (b < 0) ? 0 : ((b > 511) ? 511 : b);
            atomicAdd(&hist[bin0], 1u);
        }
        __syncthreads();                        // B3: histogram complete

        // ---- P5: exclusive prefix-sum over 512 bins
        {
            const u32 hv = hist[tid];
            u32 sc = hv;
#pragma unroll
            for (int d = 1; d < 64; d <<= 1) {
                const u32 t = __shfl_up(sc, (unsigned)d, 64);
                if (lane >= d) sc += t;
            }
            if (lane == 63) wsum8[grp] = sc;
            __syncthreads();                    // B4
            u32 woff = 0;
#pragma unroll
            for (int w = 0; w < 7; ++w) woff += (w < grp) ? wsum8[w] : 0u;
            hist[tid] = sc + woff - hv;         // exclusive cum (own slot)
        }
        __syncthreads();                        // B5: cum ready

        u32 base = 0, nxt = 0;
        if (valid) {
            base = hist[bin0];
            nxt  = (bin0 < 511) ? hist[bin0 + 1] : (u32)kkprev;
            const u32 pos = base + atomicAdd(&hoff[bin0], 1u);
            keyv[pos] = rec0;                   // in-bin order irrelevant (counted)
        }
        __syncthreads();                        // B6: records placed

        u32 rank = 0xFFFFFFFFu;
        if (valid) {
            u32 r = base;
            for (u32 j = base; j < nxt; ++j) r += (keyv[j] < rec0) ? 1u : 0u;
            rank = r;
        }
        __syncthreads();                        // B6.5: keyv reads done (pool aliases it)

        // ---- P6: compaction permute + fp16 gate copy + remap + zero tail rows
        if (tid >= kk && tid < ((kk + 15) & ~15))
            pool[tid] = make_uint4(0u, 0u, 0u, 0u);
        if (valid) {
            if (rank < (u32)kk) {
                const float w0 = v0 * s0, w1 = v1 * s0, w2 = v2 * s0, w3 = v3 * s0;
                const float w4 = v4 * s0, w5 = v5 * s0, w6 = v6 * s0, w7 = v7 * s0;
                Clo[rank] = make_float4(w0, w1, w2, w3);
                Chi[rank] = make_float4(w4, w5, w6, w7);
                f16x8 cv;
                cv[0] = (_Float16)w0; cv[1] = (_Float16)w1;
                cv[2] = (_Float16)w2; cv[3] = (_Float16)w3;
                cv[4] = (_Float16)w4; cv[5] = (_Float16)w5;
                cv[6] = (_Float16)w6; cv[7] = (_Float16)w7;
                *reinterpret_cast<f16x8*>(&pool[rank]) = cv;
                orig16[rank] = (u16)me;
                remap[tid]   = (u16)rank;       // prev slot -> new slot
            } else {
                remap[tid] = (u16)SENT;
            }
        }
        __syncthreads();                        // B7: pool/C/maps ready

        // ---- P7: gate matmul on MFMA (bias folded into C) + softmax-sum epilogue
        {
            float es = 0.f, ws = 0.f;
            const int NT = (kk + 15) >> 4;
            const f32x4 cini = {bgc, bgc, bgc, bgc};
            for (int nt = ntb; nt < NT; nt += 2) {
                const f16x8 af = *reinterpret_cast<const f16x8*>(&pool[nt * 16 + (lane & 15)]);
                const f32x4 d = __builtin_amdgcn_mfma_f32_16x16x32_f16(af, wgf, cini, 0, 0, 0);
                const int rb = nt * 16 + ((lane >> 4) << 2);   // D row base (verified layout)
#pragma unroll
                for (int r = 0; r < 4; ++r) {
                    const float gv = d[r];
                    const float e = (rb + r < kk) ? __expf(gv) : 0.f;
                    es += e;
                    ws = fmaf(e, gv, ws);
                }
            }
            es += __shfl_xor(es, 16, 64); ws += __shfl_xor(ws, 16, 64);
            es += __shfl_xor(es, 32, 64); ws += __shfl_xor(ws, 32, 64);
            if (lane < 16) {
                r1[grp * 16 + lane] = es;       // dead slots Clo[448..480)
                r2[grp * 16 + lane] = ws;
            }
            __syncthreads();                    // B8: partials ready
            if (tid < 64) {
                const float est = r1[tid] + r1[tid + 64];
                const float wst = r2[tid] + r2[tid + 64];
                out_acc += wst / est;
            }
        }

        kkprev = kk;
    }

    if (tid < 64) out[(size_t)g * 64 + tid] = out_acc;
}

extern "C" void kernel_launch(void* const* d_in, const int* in_sizes, int n_in,
                              void* d_out, int out_size, void* d_ws, size_t ws_size,
                              hipStream_t stream) {
    const float* x    = (const float*)d_in[0];
    const float* Wc   = (const float*)d_in[1];
    const float* bc   = (const float*)d_in[2];
    const float* pvec = (const float*)d_in[3];
    const float* Wg   = (const float*)d_in[4];
    const float* bg   = (const float*)d_in[5];
    const int*   ei   = (const int*)d_in[6];
    float* out = (float*)d_out;

    gce_kernel<<<dim3(1024), dim3(NTHREADS), 0, stream>>>(x, Wc, bc, pvec, Wg, bg, ei, out);
}

// Round 20
// 120.118 us; speedup vs baseline: 1.1564x; 1.1564x over previous
//
#include <hip/hip_runtime.h>
#include <stdint.h>

typedef unsigned long long ull;
typedef unsigned int u32;
typedef unsigned short u16;
typedef _Float16 f16x8 __attribute__((ext_vector_type(8)));
typedef float f32x4 __attribute__((ext_vector_type(4)));

#define NPGC 512
#define EPGC 4096
#define NTHREADS 512
#define ETOT 4194304
#define ADJCAP 4608           // 4096 edges + <=1 pad per row (pair-padded)
#define CGCAP 416             // ceil(410/16)*16 fp16x8 gate rows
#define SENT 512              // sentinel slot (zero features)

__global__ __launch_bounds__(NTHREADS, 6)
void gce_kernel(const float* __restrict__ x,
                const float* __restrict__ Wc,
                const float* __restrict__ bc,
                const float* __restrict__ pvec,
                const float* __restrict__ Wg,
                const float* __restrict__ bg,
                const int* __restrict__ ei,
                float* __restrict__ out)
{
    __shared__ float4 Clo[NPGC + 1];             //  8208 B features ch0-3 (by slot); 512 = zeros
    __shared__ float4 Chi[NPGC + 1];             //  8208 B features ch4-7; [448..512) = r1/r2 in P7
    __shared__ __align__(4) u16 adjl[ADJCAP];    //  9216 B CSR, pair-padded, slot-rewritten/layer
    __shared__ u16    indptr[NPGC + 1];          //  1026 B row offsets (by original id)
    __shared__ u16    remap[NPGC + 1];           //  1026 B prev slot -> new slot (SENT = dropped)
    __shared__ u16    orig16[NPGC];              //  1024 B slot -> original id
    __shared__ __align__(16) uint4 pool[CGCAP];  //  6656 B: keyv u64[512] | Cg fp16x8[416]
    __shared__ u32    hist[NPGC];                //  2048 B histogram/cum
    __shared__ u32    hoff[NPGC];                //  2048 B placement offsets
    __shared__ u32    wsum8[8];                  //    32 B cross-wave prefix
    // total ~39.5 KB -> 4 blocks/CU

    const int tid  = threadIdx.x;
    const int lane = tid & 63;
    const int grp  = tid >> 6;      // wave id (0..7)
    const int g    = blockIdx.x;

    ull* keyv = reinterpret_cast<ull*>(pool);
    // r1/r2 in dead feature slots: ranks >= 410 never written/read after layer-0 compaction
    float* r1 = reinterpret_cast<float*>(&Clo[448]);
    float* r2 = reinterpret_cast<float*>(&Chi[448]);

    // ---- MFMA gate operands: wave's channel tile ct = grp&3, node-tile start ntb
    const int ct  = grp & 3;
    const int ntb = grp >> 2;
    f16x8 wgf;                       // B-frag: lanes 0-15 = Wg[0..7][ct*16+lane]; rest 0 (k>=8 dead)
    if (lane < 16) {
#pragma unroll
        for (int j = 0; j < 8; ++j) wgf[j] = (_Float16)Wg[j * 64 + ct * 16 + lane];
    } else {
#pragma unroll
        for (int j = 0; j < 8; ++j) wgf[j] = (_Float16)0.f;
    }
    const float bgc = bg[ct * 16 + (lane & 15)];

    // ---- preload this thread's 8 edges, packed (src | dst<<16), local ids
    uint32_t er[8];
    {
        const int* rowp = ei;
        const int* colp = ei + ETOT;
        const size_t eb = (size_t)g * EPGC + (size_t)tid * 8;
#pragma unroll
        for (int i = 0; i < 2; ++i) {
            int4 r4 = *reinterpret_cast<const int4*>(rowp + eb + i * 4);
            int4 c4 = *reinterpret_cast<const int4*>(colp + eb + i * 4);
            er[i * 4 + 0] = (uint32_t)(r4.x & 511) | ((uint32_t)(c4.x & 511) << 16);
            er[i * 4 + 1] = (uint32_t)(r4.y & 511) | ((uint32_t)(c4.y & 511) << 16);
            er[i * 4 + 2] = (uint32_t)(r4.z & 511) | ((uint32_t)(c4.z & 511) << 16);
            er[i * 4 + 3] = (uint32_t)(r4.w & 511) | ((uint32_t)(c4.w & 511) << 16);
        }
    }

    // ---- init: features (slot = original id at layer 0), maps, zero slot
    {
        const float* xr = x + ((size_t)g * NPGC + tid) * 8;
        Clo[tid] = *reinterpret_cast<const float4*>(xr);
        Chi[tid] = *reinterpret_cast<const float4*>(xr + 4);
        orig16[tid] = (u16)tid;
        hist[tid] = 0u;
        if (tid == 0) {
            remap[SENT] = (u16)SENT;
            Clo[SENT] = make_float4(0.f, 0.f, 0.f, 0.f);
            Chi[SENT] = make_float4(0.f, 0.f, 0.f, 0.f);
        }
    }
    __syncthreads();

    // ---- build pair-padded in-edge CSR once (pad entry = SENT)
#pragma unroll
    for (int i = 0; i < 8; ++i) atomicAdd(&hist[er[i] >> 16], 1u);
    __syncthreads();
    {
        const u32 hv  = hist[tid];
        const u32 hvp = (hv + 1u) & ~1u;        // pair-padded row length
        u32 sc = hvp;
#pragma unroll
        for (int d = 1; d < 64; d <<= 1) {
            const u32 t = __shfl_up(sc, (unsigned)d, 64);
            if (lane >= d) sc += t;
        }
        if (lane == 63) wsum8[grp] = sc;
        __syncthreads();
        u32 woff = 0;
#pragma unroll
        for (int w = 0; w < 7; ++w) woff += (w < grp) ? wsum8[w] : 0u;
        const u32 excl = sc + woff - hvp;
        indptr[tid] = (u16)excl;
        hoff[tid]   = excl;
        if (tid == NPGC - 1) indptr[NPGC] = (u16)(excl + hvp);
    }
    __syncthreads();
#pragma unroll
    for (int i = 0; i < 8; ++i) {
        const u32 d = er[i] >> 16, s = er[i] & 0xffffu;
        const u32 pos = atomicAdd(&hoff[d], 1u);
        adjl[pos] = (u16)s;                     // original id = layer-0 slot
    }
    __syncthreads();
    for (u32 j = hoff[tid]; j < (u32)indptr[tid + 1]; ++j) adjl[j] = (u16)SENT;
    // (no barrier needed: pads are in this thread's own row; B2 covers cross-thread reads)

    int   kkprev  = NPGC;
    float out_acc = 0.f;

#pragma unroll 1
    for (int layer = 0; layer < 4; ++layer) {
        const float* Wl = Wc + layer * 64;
        const float* bl = bc + layer * 8;
        const float* pl = pvec + layer * 8;
        const int kk = (layer == 0) ? 410 : (layer == 1) ? 328 : (layer == 2) ? 263 : 211;
        const bool valid = tid < kkprev;
        int me = 0, ib = 0, ie = 0;
        float dinv = 0.f;
        float4 slo = make_float4(0.f, 0.f, 0.f, 0.f), shi = slo;

        // ---- Phase A: (layers>0) rewrite row to new slot space + deg; scale own h
        if (valid) {
            me = orig16[tid];
            ib = indptr[me];
            ie = indptr[me + 1];
            int dg = 1;                          // self-loop
            if (layer == 0) {
                dg += (ie - ib) - ((ie > ib && adjl[ie - 1] == (u16)SENT) ? 1 : 0);
            } else {
                for (int j = ib; j < ie; j += 2) {
                    const u32 pr = *reinterpret_cast<const u32*>(&adjl[j]);
                    const u32 t0 = remap[pr & 0xffffu];
                    const u32 t1 = remap[pr >> 16];
                    dg += (t0 != SENT) + (t1 != SENT);
                    *reinterpret_cast<u32*>(&adjl[j]) = t0 | (t1 << 16);
                }
            }
            dinv = rsqrtf((float)dg);
            slo = Clo[tid]; shi = Chi[tid];
            slo.x *= dinv; slo.y *= dinv; slo.z *= dinv; slo.w *= dinv;
            shi.x *= dinv; shi.y *= dinv; shi.z *= dinv; shi.w *= dinv;
            Clo[tid] = slo; Chi[tid] = shi;      // h' = h * dinv
        }
        hist[tid] = 0u;
        hoff[tid] = 0u;
        __syncthreads();                        // B2: h' + rewritten rows + clears visible

        // ---- Phase B: direct-slot gather; @W; bias/relu/score/key
        float v0 = 0.f, v1 = 0.f, v2 = 0.f, v3 = 0.f,
              v4 = 0.f, v5 = 0.f, v6 = 0.f, v7 = 0.f;
        float s0 = 0.f;
        int bin0 = 0;
        ull rec0 = 0;
        if (valid) {
            float a0 = slo.x, a1 = slo.y, a2 = slo.z, a3 = slo.w;
            float a4 = shi.x, a5 = shi.y, a6 = shi.z, a7 = shi.w;
            for (int j = ib; j < ie; j += 2) {
                const u32 pr = *reinterpret_cast<const u32*>(&adjl[j]);
                const int t0 = pr & 0xffffu, t1 = pr >> 16;
                const float4 l0 = Clo[t0], h0 = Chi[t0];   // SENT -> zeros
                const float4 l1 = Clo[t1], h1 = Chi[t1];
                a0 += l0.x + l1.x; a1 += l0.y + l1.y;
                a2 += l0.z + l1.z; a3 += l0.w + l1.w;
                a4 += h0.x + h1.x; a5 += h0.y + h1.y;
                a6 += h0.z + h1.z; a7 += h0.w + h1.w;
            }
            a0 *= dinv; a1 *= dinv; a2 *= dinv; a3 *= dinv;
            a4 *= dinv; a5 *= dinv; a6 *= dinv; a7 *= dinv;
            const float av[8] = {a0, a1, a2, a3, a4, a5, a6, a7};
            float yv[8];
#pragma unroll
            for (int k = 0; k < 8; ++k) {
                float acc = 0.f;
#pragma unroll
                for (int j2 = 0; j2 < 8; ++j2) acc += av[j2] * Wl[j2 * 8 + k];
                yv[k] = acc;
            }
            float pv[8], ss = 0.f;
#pragma unroll
            for (int k = 0; k < 8; ++k) { pv[k] = pl[k]; ss += pv[k] * pv[k]; }
            float dot = 0.f;
            v0 = fmaxf(yv[0] + bl[0], 0.f); dot += v0 * pv[0];
            v1 = fmaxf(yv[1] + bl[1], 0.f); dot += v1 * pv[1];
            v2 = fmaxf(yv[2] + bl[2], 0.f); dot += v2 * pv[2];
            v3 = fmaxf(yv[3] + bl[3], 0.f); dot += v3 * pv[3];
            v4 = fmaxf(yv[4] + bl[4], 0.f); dot += v4 * pv[4];
            v5 = fmaxf(yv[5] + bl[5], 0.f); dot += v5 * pv[5];
            v6 = fmaxf(yv[6] + bl[6], 0.f); dot += v6 * pv[6];
            v7 = fmaxf(yv[7] + bl[7], 0.f); dot += v7 * pv[7];
            // fast tanh: monotone, NaN-free (e2=inf -> 1, e2=0 -> -1)
            const float xx = dot * rsqrtf(ss);
            const float e2 = __expf(2.0f * xx);
            s0 = 1.0f - 2.0f * __builtin_amdgcn_rcpf(e2 + 1.0f);
            const unsigned ub  = __float_as_uint(s0);
            const unsigned asc = (ub & 0x80000000u) ? ~ub : (ub | 0x80000000u);
            rec0 = ((ull)(~asc) << 32) | (u32)me;    // desc score; ties by original id asc
            int b = (int)((1.0f - s0) * 256.0f);     // monotone with key
            bin0 = (b < 0) ? 0 : ((b > 511) ? 511 : b);
            atomicAdd(&hist[bin0], 1u);
        }
        __syncthreads();                        // B3: histogram complete

        // ---- P5: exclusive prefix-sum over 512 bins
        {
            const u32 hv = hist[tid];
            u32 sc = hv;
#pragma unroll
            for (int d = 1; d < 64; d <<= 1) {
                const u32 t = __shfl_up(sc, (unsigned)d, 64);
                if (lane >= d) sc += t;
            }
            if (lane == 63) wsum8[grp] = sc;
            __syncthreads();                    // B4
            u32 woff = 0;
#pragma unroll
            for (int w = 0; w < 7; ++w) woff += (w < grp) ? wsum8[w] : 0u;
            hist[tid] = sc + woff - hv;         // exclusive cum (own slot)
        }
        __syncthreads();                        // B5: cum ready

        u32 base = 0, nxt = 0;
        if (valid) {
            base = hist[bin0];
            nxt  = (bin0 < 511) ? hist[bin0 + 1] : (u32)kkprev;
            const u32 pos = base + atomicAdd(&hoff[bin0], 1u);
            keyv[pos] = rec0;                   // in-bin order irrelevant (counted)
        }
        __syncthreads();                        // B6: records placed

        u32 rank = 0xFFFFFFFFu;
        if (valid) {
            u32 r = base;
            for (u32 j = base; j < nxt; ++j) r += (keyv[j] < rec0) ? 1u : 0u;
            rank = r;
        }
        __syncthreads();                        // B6.5: keyv reads done (pool aliases it)

        // ---- P6: compaction permute + fp16 gate copy + remap + zero tail rows
        if (tid >= kk && tid < ((kk + 15) & ~15))
            pool[tid] = make_uint4(0u, 0u, 0u, 0u);
        if (valid) {
            if (rank < (u32)kk) {
                const float w0 = v0 * s0, w1 = v1 * s0, w2 = v2 * s0, w3 = v3 * s0;
                const float w4 = v4 * s0, w5 = v5 * s0, w6 = v6 * s0, w7 = v7 * s0;
                Clo[rank] = make_float4(w0, w1, w2, w3);
                Chi[rank] = make_float4(w4, w5, w6, w7);
                f16x8 cv;
                cv[0] = (_Float16)w0; cv[1] = (_Float16)w1;
                cv[2] = (_Float16)w2; cv[3] = (_Float16)w3;
                cv[4] = (_Float16)w4; cv[5] = (_Float16)w5;
                cv[6] = (_Float16)w6; cv[7] = (_Float16)w7;
                *reinterpret_cast<f16x8*>(&pool[rank]) = cv;
                orig16[rank] = (u16)me;
                remap[tid]   = (u16)rank;       // prev slot -> new slot
            } else {
                remap[tid] = (u16)SENT;
            }
        }
        __syncthreads();                        // B7: pool/C/maps ready

        // ---- P7: gate matmul on MFMA (bias folded into C) + softmax-sum epilogue
        {
            float es = 0.f, ws = 0.f;
            const int NT = (kk + 15) >> 4;
            const f32x4 cini = {bgc, bgc, bgc, bgc};
            for (int nt = ntb; nt < NT; nt += 2) {
                const f16x8 af = *reinterpret_cast<const f16x8*>(&pool[nt * 16 + (lane & 15)]);
                const f32x4 d = __builtin_amdgcn_mfma_f32_16x16x32_f16(af, wgf, cini, 0, 0, 0);
                const int rb = nt * 16 + ((lane >> 4) << 2);   // D row base (verified layout)
#pragma unroll
                for (int r = 0; r < 4; ++r) {
                    const float gv = d[r];
                    const float e = (rb + r < kk) ? __expf(gv) : 0.f;
                    es += e;
                    ws = fmaf(e, gv, ws);
                }
            }
            es += __shfl_xor(es, 16, 64); ws += __shfl_xor(ws, 16, 64);
            es += __shfl_xor(es, 32, 64); ws += __shfl_xor(ws, 32, 64);
            if (lane < 16) {
                r1[grp * 16 + lane] = es;       // dead slots Clo[448..480)
                r2[grp * 16 + lane] = ws;
            }
            __syncthreads();                    // B8: partials ready
            if (tid < 64) {
                const float est = r1[tid] + r1[tid + 64];
                const float wst = r2[tid] + r2[tid + 64];
                out_acc += wst / est;
            }
        }

        kkprev = kk;
    }

    if (tid < 64) out[(size_t)g * 64 + tid] = out_acc;
}

extern "C" void kernel_launch(void* const* d_in, const int* in_sizes, int n_in,
                              void* d_out, int out_size, void* d_ws, size_t ws_size,
                              hipStream_t stream) {
    const float* x    = (const float*)d_in[0];
    const float* Wc   = (const float*)d_in[1];
    const float* bc   = (const float*)d_in[2];
    const float* pvec = (const float*)d_in[3];
    const float* Wg   = (const float*)d_in[4];
    const float* bg   = (const float*)d_in[5];
    const int*   ei   = (const int*)d_in[6];
    float* out = (float*)d_out;

    gce_kernel<<<dim3(1024), dim3(NTHREADS), 0, stream>>>(x, Wc, bc, pvec, Wg, bg, ei, out);
}

// Round 21
// 114.844 us; speedup vs baseline: 1.2095x; 1.0459x over previous
//
#include <hip/hip_runtime.h>
#include <hip/hip_fp16.h>
#include <stdint.h>

typedef unsigned long long ull;
typedef unsigned int u32;
typedef unsigned short u16;
typedef _Float16 f16x8 __attribute__((ext_vector_type(8)));
typedef float f32x4 __attribute__((ext_vector_type(4)));

#define NPGC 512
#define EPGC 4096
#define NTHREADS 512
#define ETOT 4194304
#define ADJCAP 4608           // 4096 edges + <=1 pad per row (pair-padded)
#define SENT 512              // sentinel slot (zero features)

__global__ __launch_bounds__(NTHREADS, 6)
void gce_kernel(const float* __restrict__ x,
                const float* __restrict__ Wc,
                const float* __restrict__ bc,
                const float* __restrict__ pvec,
                const float* __restrict__ Wg,
                const float* __restrict__ bg,
                const int* __restrict__ ei,
                float* __restrict__ out)
{
    __shared__ __align__(16) uint4 Cf[NPGC + 1]; //  8208 B packed fp16x8 features (by slot); 512 = 0
    __shared__ __align__(4) u16 adjl[ADJCAP];    //  9216 B CSR, pair-padded, slot-rewritten/layer
    __shared__ u16    indptr[NPGC + 1];          //  1026 B row offsets (by original id)
    __shared__ u16    remap[NPGC + 1];           //  1026 B prev slot -> new slot (SENT = dropped)
    __shared__ u16    orig16[NPGC];              //  1024 B slot -> original id
    __shared__ __align__(16) ull keyv[NPGC];     //  4096 B rank records (dedicated)
    __shared__ u32    hist[NPGC];                //  2048 B histogram -> cum (in place)
    __shared__ u32    hoff[NPGC];                //  2048 B CSR-build placement only
    __shared__ float  r1[128], r2[128];          //  1024 B P7 partials (dedicated)
    __shared__ u32    wsum8[8];                  //    32 B cross-wave prefix
    // total ~29.8 KB -> 4 blocks/CU (wave-capped)

    const int tid  = threadIdx.x;
    const int lane = tid & 63;
    const int grp  = tid >> 6;      // wave id (0..7)
    const int g    = blockIdx.x;

    // ---- MFMA gate operands: wave's channel tile ct = grp&3, node-tile start ntb
    const int ct  = grp & 3;
    const int ntb = grp >> 2;
    f16x8 wgf;                       // B-frag: lanes 0-15 = Wg[0..7][ct*16+lane]; rest 0 (k>=8 dead)
    if (lane < 16) {
#pragma unroll
        for (int j = 0; j < 8; ++j) wgf[j] = (_Float16)Wg[j * 64 + ct * 16 + lane];
    } else {
#pragma unroll
        for (int j = 0; j < 8; ++j) wgf[j] = (_Float16)0.f;
    }
    const float bgc = bg[ct * 16 + (lane & 15)];

    // ---- preload this thread's 8 edges, packed (src | dst<<16), local ids
    uint32_t er[8];
    {
        const int* rowp = ei;
        const int* colp = ei + ETOT;
        const size_t eb = (size_t)g * EPGC + (size_t)tid * 8;
#pragma unroll
        for (int i = 0; i < 2; ++i) {
            int4 r4 = *reinterpret_cast<const int4*>(rowp + eb + i * 4);
            int4 c4 = *reinterpret_cast<const int4*>(colp + eb + i * 4);
            er[i * 4 + 0] = (uint32_t)(r4.x & 511) | ((uint32_t)(c4.x & 511) << 16);
            er[i * 4 + 1] = (uint32_t)(r4.y & 511) | ((uint32_t)(c4.y & 511) << 16);
            er[i * 4 + 2] = (uint32_t)(r4.z & 511) | ((uint32_t)(c4.z & 511) << 16);
            er[i * 4 + 3] = (uint32_t)(r4.w & 511) | ((uint32_t)(c4.w & 511) << 16);
        }
    }

    // ---- init: features packed fp16 (slot = original id at layer 0), maps, zero slot
    {
        const float* xr = x + ((size_t)g * NPGC + tid) * 8;
        float4 a = *reinterpret_cast<const float4*>(xr);
        float4 b = *reinterpret_cast<const float4*>(xr + 4);
        union { __half2 h[4]; uint4 u; } cv;
        cv.h[0] = __floats2half2_rn(a.x, a.y);
        cv.h[1] = __floats2half2_rn(a.z, a.w);
        cv.h[2] = __floats2half2_rn(b.x, b.y);
        cv.h[3] = __floats2half2_rn(b.z, b.w);
        Cf[tid] = cv.u;
        orig16[tid] = (u16)tid;
        hist[tid] = 0u;
        if (tid == 0) {
            remap[SENT] = (u16)SENT;
            Cf[SENT] = make_uint4(0u, 0u, 0u, 0u);
        }
    }
    __syncthreads();

    // ---- build pair-padded in-edge CSR once (pad entry = SENT)
#pragma unroll
    for (int i = 0; i < 8; ++i) atomicAdd(&hist[er[i] >> 16], 1u);
    __syncthreads();
    {
        const u32 hv  = hist[tid];
        const u32 hvp = (hv + 1u) & ~1u;        // pair-padded row length
        u32 sc = hvp;
#pragma unroll
        for (int d = 1; d < 64; d <<= 1) {
            const u32 t = __shfl_up(sc, (unsigned)d, 64);
            if (lane >= d) sc += t;
        }
        if (lane == 63) wsum8[grp] = sc;
        __syncthreads();
        u32 woff = 0;
#pragma unroll
        for (int w = 0; w < 7; ++w) woff += (w < grp) ? wsum8[w] : 0u;
        const u32 excl = sc + woff - hvp;
        indptr[tid] = (u16)excl;
        hoff[tid]   = excl;
        if (tid == NPGC - 1) indptr[NPGC] = (u16)(excl + hvp);
    }
    __syncthreads();
#pragma unroll
    for (int i = 0; i < 8; ++i) {
        const u32 d = er[i] >> 16, s = er[i] & 0xffffu;
        const u32 pos = atomicAdd(&hoff[d], 1u);
        adjl[pos] = (u16)s;                     // original id = layer-0 slot
    }
    __syncthreads();
    for (u32 j = hoff[tid]; j < (u32)indptr[tid + 1]; ++j) adjl[j] = (u16)SENT;
    // hist cleared per-layer below; hoff no longer used after build

    int   kkprev  = NPGC;
    float out_acc = 0.f;

#pragma unroll 1
    for (int layer = 0; layer < 4; ++layer) {
        const float* Wl = Wc + layer * 64;
        const float* bl = bc + layer * 8;
        const float* pl = pvec + layer * 8;
        const int kk = (layer == 0) ? 410 : (layer == 1) ? 328 : (layer == 2) ? 263 : 211;
        const bool valid = tid < kkprev;
        int me = 0, ib = 0, ie = 0;
        float dinv = 0.f;
        union { __half2 h[4]; uint4 u; } own;
        own.u = make_uint4(0u, 0u, 0u, 0u);

        // ---- Phase A: (layers>0) rewrite row to new slot space + deg; scale own h (fp16)
        if (valid) {
            me = orig16[tid];
            ib = indptr[me];
            ie = indptr[me + 1];
            int dg = 1;                          // self-loop
            if (layer == 0) {
                dg += (ie - ib) - ((ie > ib && adjl[ie - 1] == (u16)SENT) ? 1 : 0);
            } else {
                for (int j = ib; j < ie; j += 2) {
                    const u32 pr = *reinterpret_cast<const u32*>(&adjl[j]);
                    const u32 t0 = remap[pr & 0xffffu];
                    const u32 t1 = remap[pr >> 16];
                    dg += (t0 != SENT) + (t1 != SENT);
                    *reinterpret_cast<u32*>(&adjl[j]) = t0 | (t1 << 16);
                }
            }
            dinv = rsqrtf((float)dg);
            own.u = Cf[tid];
            const __half2 dh = __float2half2_rn(dinv);
            own.h[0] = __hmul2(own.h[0], dh);
            own.h[1] = __hmul2(own.h[1], dh);
            own.h[2] = __hmul2(own.h[2], dh);
            own.h[3] = __hmul2(own.h[3], dh);
            Cf[tid] = own.u;                     // h' = h * dinv
        }
        hist[tid] = 0u;
        __syncthreads();                        // B2: h' + rewritten rows + clears visible

        // ---- Phase B: fp16 packed gather; @W (f32); bias/relu/score/key
        float v0 = 0.f, v1 = 0.f, v2 = 0.f, v3 = 0.f,
              v4 = 0.f, v5 = 0.f, v6 = 0.f, v7 = 0.f;
        float s0 = 0.f;
        int bin0 = 0;
        u32 posInBin = 0;
        ull rec0 = 0;
        if (valid) {
            __half2 s01 = own.h[0], s23 = own.h[1], s45 = own.h[2], s67 = own.h[3];
            for (int j = ib; j < ie; j += 2) {
                const u32 pr = *reinterpret_cast<const u32*>(&adjl[j]);
                const int t0 = pr & 0xffffu, t1 = pr >> 16;
                union { __half2 h[4]; uint4 u; } c0, c1;
                c0.u = Cf[t0];                   // SENT -> zeros
                c1.u = Cf[t1];
                s01 = __hadd2(s01, __hadd2(c0.h[0], c1.h[0]));
                s23 = __hadd2(s23, __hadd2(c0.h[1], c1.h[1]));
                s45 = __hadd2(s45, __hadd2(c0.h[2], c1.h[2]));
                s67 = __hadd2(s67, __hadd2(c0.h[3], c1.h[3]));
            }
            const float a0 = __low2float(s01) * dinv, a1 = __high2float(s01) * dinv;
            const float a2 = __low2float(s23) * dinv, a3 = __high2float(s23) * dinv;
            const float a4 = __low2float(s45) * dinv, a5 = __high2float(s45) * dinv;
            const float a6 = __low2float(s67) * dinv, a7 = __high2float(s67) * dinv;
            const float av[8] = {a0, a1, a2, a3, a4, a5, a6, a7};
            float yv[8];
#pragma unroll
            for (int k = 0; k < 8; ++k) {
                float acc = 0.f;
#pragma unroll
                for (int j2 = 0; j2 < 8; ++j2) acc += av[j2] * Wl[j2 * 8 + k];
                yv[k] = acc;
            }
            float pv[8], ss = 0.f;
#pragma unroll
            for (int k = 0; k < 8; ++k) { pv[k] = pl[k]; ss += pv[k] * pv[k]; }
            float dot = 0.f;
            v0 = fmaxf(yv[0] + bl[0], 0.f); dot += v0 * pv[0];
            v1 = fmaxf(yv[1] + bl[1], 0.f); dot += v1 * pv[1];
            v2 = fmaxf(yv[2] + bl[2], 0.f); dot += v2 * pv[2];
            v3 = fmaxf(yv[3] + bl[3], 0.f); dot += v3 * pv[3];
            v4 = fmaxf(yv[4] + bl[4], 0.f); dot += v4 * pv[4];
            v5 = fmaxf(yv[5] + bl[5], 0.f); dot += v5 * pv[5];
            v6 = fmaxf(yv[6] + bl[6], 0.f); dot += v6 * pv[6];
            v7 = fmaxf(yv[7] + bl[7], 0.f); dot += v7 * pv[7];
            // fast tanh (monotone, NaN-free)
            const float xx = dot * rsqrtf(ss);
            const float e2 = __expf(2.0f * xx);
            s0 = 1.0f - 2.0f * __builtin_amdgcn_rcpf(e2 + 1.0f);
            const unsigned ub  = __float_as_uint(s0);
            const unsigned asc = (ub & 0x80000000u) ? ~ub : (ub | 0x80000000u);
            rec0 = ((ull)(~asc) << 32) | (u32)me;    // desc score; ties by original id asc
            int b = (int)((1.0f - s0) * 256.0f);     // monotone with key
            bin0 = (b < 0) ? 0 : ((b > 511) ? 511 : b);
            posInBin = atomicAdd(&hist[bin0], 1u);   // count + placement offset in one
        }
        __syncthreads();                        // B3: histogram complete

        // ---- P5: exclusive prefix-sum over 512 bins (in place)
        {
            const u32 hv = hist[tid];
            u32 sc = hv;
#pragma unroll
            for (int d = 1; d < 64; d <<= 1) {
                const u32 t = __shfl_up(sc, (unsigned)d, 64);
                if (lane >= d) sc += t;
            }
            if (lane == 63) wsum8[grp] = sc;
            __syncthreads();                    // B4
            u32 woff = 0;
#pragma unroll
            for (int w = 0; w < 7; ++w) woff += (w < grp) ? wsum8[w] : 0u;
            hist[tid] = sc + woff - hv;         // exclusive cum (own slot)
        }
        __syncthreads();                        // B5: cum ready

        u32 base = 0, nxt = 0;
        if (valid) {
            base = hist[bin0];
            nxt  = (bin0 < 511) ? hist[bin0 + 1] : (u32)kkprev;
            keyv[base + posInBin] = rec0;       // in-bin order irrelevant (counted)
        }
        __syncthreads();                        // B6: records placed

        u32 rank = 0xFFFFFFFFu;
        if (valid) {
            u32 r = base;
            for (u32 j = base; j < nxt; ++j) r += (keyv[j] < rec0) ? 1u : 0u;
            rank = r;
        }
        // (no B6.5: keyv is dedicated; P6 touches only Cf/orig16/remap)

        // ---- P6: compaction permute (single fp16 write) + remap
        if (valid) {
            if (rank < (u32)kk) {
                union { __half2 h[4]; uint4 u; } cv;
                cv.h[0] = __floats2half2_rn(v0 * s0, v1 * s0);
                cv.h[1] = __floats2half2_rn(v2 * s0, v3 * s0);
                cv.h[2] = __floats2half2_rn(v4 * s0, v5 * s0);
                cv.h[3] = __floats2half2_rn(v6 * s0, v7 * s0);
                Cf[rank] = cv.u;
                orig16[rank] = (u16)me;
                remap[tid]   = (u16)rank;       // prev slot -> new slot
            } else {
                remap[tid] = (u16)SENT;
            }
        }
        __syncthreads();                        // B7: Cf/maps ready

        // ---- P7: gate matmul on MFMA directly from Cf (stale rows masked in epilogue)
        {
            float es = 0.f, ws = 0.f;
            const int NT = (kk + 15) >> 4;
            const f32x4 cini = {bgc, bgc, bgc, bgc};
            for (int nt = ntb; nt < NT; nt += 2) {
                const f16x8 af = *reinterpret_cast<const f16x8*>(&Cf[nt * 16 + (lane & 15)]);
                const f32x4 d = __builtin_amdgcn_mfma_f32_16x16x32_f16(af, wgf, cini, 0, 0, 0);
                const int rb = nt * 16 + ((lane >> 4) << 2);   // D row base (verified layout)
#pragma unroll
                for (int r = 0; r < 4; ++r) {
                    const float gv = d[r];
                    const float e = (rb + r < kk) ? __expf(gv) : 0.f;  // masks stale rows
                    es += e;
                    ws = fmaf(e, gv, ws);
                }
            }
            es += __shfl_xor(es, 16, 64); ws += __shfl_xor(ws, 16, 64);
            es += __shfl_xor(es, 32, 64); ws += __shfl_xor(ws, 32, 64);
            if (lane < 16) {
                r1[grp * 16 + lane] = es;
                r2[grp * 16 + lane] = ws;
            }
            __syncthreads();                    // B8: partials ready
            if (tid < 64) {
                const float est = r1[tid] + r1[tid + 64];
                const float wst = r2[tid] + r2[tid + 64];
                out_acc += wst / est;
            }
        }

        kkprev = kk;
    }

    if (tid < 64) out[(size_t)g * 64 + tid] = out_acc;
}

extern "C" void kernel_launch(void* const* d_in, const int* in_sizes, int n_in,
                              void* d_out, int out_size, void* d_ws, size_t ws_size,
                              hipStream_t stream) {
    const float* x    = (const float*)d_in[0];
    const float* Wc   = (const float*)d_in[1];
    const float* bc   = (const float*)d_in[2];
    const float* pvec = (const float*)d_in[3];
    const float* Wg   = (const float*)d_in[4];
    const float* bg   = (const float*)d_in[5];
    const int*   ei   = (const int*)d_in[6];
    float* out = (float*)d_out;

    gce_kernel<<<dim3(1024), dim3(NTHREADS), 0, stream>>>(x, Wc, bc, pvec, Wg, bg, ei, out);
}